// Round 6
// baseline (149.155 us; speedup 1.0000x reference)
//
#include <hip/hip_runtime.h>
#include <hip/hip_bf16.h>

#define NBAGS 16384
#define OUT_STRIDE 288

typedef float v2f __attribute__((ext_vector_type(2)));

struct Ptrs {
    const float* W[4];
    const int* ids[4];
    const int* lens[4];
    int* starts[4];
    float* out;
};

// Brute-force chunked exclusive scan: grid = 4 tables x 256 chunks.
__global__ void __launch_bounds__(256) scan_kernel(Ptrs p) {
    const int t = blockIdx.x >> 8;
    const int c = blockIdx.x & 255;
    const int* __restrict__ lens = p.lens[t];
    int* __restrict__ starts = p.starts[t];
    const int tid = threadIdx.x;
    const int P = c * 64;

    __shared__ int red[256];
    int s = 0;
    for (int k = tid; k < P; k += 256) s += lens[k];
    red[tid] = s;
    __syncthreads();
    for (int off = 128; off > 0; off >>= 1) {
        if (tid < off) red[tid] += red[tid + off];
        __syncthreads();
    }
    const int prefix = red[0];

    if (tid < 64) {
        const int v = lens[P + tid];
        int inc = v;
#pragma unroll
        for (int off = 1; off < 64; off <<= 1) {
            int u = __shfl_up(inc, off, 64);
            if (tid >= off) inc += u;
        }
        starts[P + tid] = prefix + inc - v;
    }
}

__device__ __forceinline__ int rfl(int x) { return __builtin_amdgcn_readfirstlane(x); }

// ---- D=64 (tables 0,3): one wave per bag, 16 asm-clustered gathers/batch.
// ids/addresses are wave-uniform -> SMEM + SALU; dest = 1 VGPR per row.
__device__ __forceinline__ void wave_d64(const float* __restrict__ W,
    const int* __restrict__ ids, int s, int n, float* __restrict__ op, int lane)
{
    const unsigned loff = (unsigned)lane * 4u;
    float a0 = 0.f, a1 = 0.f, a2 = 0.f, a3 = 0.f;
    int j = 0;
    while (j < n) {
        float r0, r1, r2, r3, r4, r5, r6, r7, r8, r9, r10, r11, r12, r13, r14, r15;
#define ISS64(k)                                                              \
        { const int jj = j + k; const int ix = (jj < n) ? jj : (n - 1);       \
          const float* p_ = W + (size_t)ids[s + ix] * 64;                     \
          asm volatile("global_load_dword %0, %1, %2"                         \
                       : "=v"(r##k) : "v"(loff), "s"(p_)); }
        ISS64(0) ISS64(1) ISS64(2) ISS64(3) ISS64(4) ISS64(5) ISS64(6) ISS64(7)
        ISS64(8) ISS64(9) ISS64(10) ISS64(11) ISS64(12) ISS64(13) ISS64(14) ISS64(15)
#undef ISS64
        asm volatile("s_waitcnt vmcnt(0)");
        __builtin_amdgcn_sched_barrier(0);
        if (j + 16 <= n) {
            a0 += r0;  a1 += r1;  a2 += r2;  a3 += r3;
            a0 += r4;  a1 += r5;  a2 += r6;  a3 += r7;
            a0 += r8;  a1 += r9;  a2 += r10; a3 += r11;
            a0 += r12; a1 += r13; a2 += r14; a3 += r15;
        } else {
#define ACM64(k, d)                                                           \
            { const float m_ = (j + k < n) ? 1.f : 0.f;                       \
              a##d = fmaf(m_, r##k, a##d); }
            ACM64(0,0) ACM64(1,1) ACM64(2,2) ACM64(3,3)
            ACM64(4,0) ACM64(5,1) ACM64(6,2) ACM64(7,3)
            ACM64(8,0) ACM64(9,1) ACM64(10,2) ACM64(11,3)
            ACM64(12,0) ACM64(13,1) ACM64(14,2) ACM64(15,3)
#undef ACM64
        }
        j += 16;
    }
    op[lane] = (a0 + a1) + (a2 + a3);
}

// ---- D=128 (table 1): one wave per bag, dwordx2/lane, 8 gathers/batch.
__device__ __forceinline__ void wave_d128(const float* __restrict__ W,
    const int* __restrict__ ids, int s, int n, float* __restrict__ op, int lane)
{
    const unsigned loff = (unsigned)lane * 8u;
    v2f a0 = {0.f, 0.f}, a1 = {0.f, 0.f}, a2 = {0.f, 0.f}, a3 = {0.f, 0.f};
    int j = 0;
    while (j < n) {
        v2f r0, r1, r2, r3, r4, r5, r6, r7;
#define ISS128(k)                                                             \
        { const int jj = j + k; const int ix = (jj < n) ? jj : (n - 1);       \
          const float* p_ = W + (size_t)ids[s + ix] * 128;                    \
          asm volatile("global_load_dwordx2 %0, %1, %2"                       \
                       : "=v"(r##k) : "v"(loff), "s"(p_)); }
        ISS128(0) ISS128(1) ISS128(2) ISS128(3)
        ISS128(4) ISS128(5) ISS128(6) ISS128(7)
#undef ISS128
        asm volatile("s_waitcnt vmcnt(0)");
        __builtin_amdgcn_sched_barrier(0);
        if (j + 8 <= n) {
            a0 += r0; a1 += r1; a2 += r2; a3 += r3;
            a0 += r4; a1 += r5; a2 += r6; a3 += r7;
        } else {
#define ACM128(k, d)                                                          \
            { const float m_ = (j + k < n) ? 1.f : 0.f;                       \
              a##d.x = fmaf(m_, r##k.x, a##d.x);                              \
              a##d.y = fmaf(m_, r##k.y, a##d.y); }
            ACM128(0,0) ACM128(1,1) ACM128(2,2) ACM128(3,3)
            ACM128(4,0) ACM128(5,1) ACM128(6,2) ACM128(7,3)
#undef ACM128
        }
        j += 8;
    }
    const v2f a = (a0 + a1) + (a2 + a3);
    *reinterpret_cast<v2f*>(op + lane * 2) = a;
}

// ---- D=32 (table 2): one wave per TWO bags (half-wave each), vector-addressed.
__device__ __forceinline__ void wave_d32x2(const float* __restrict__ W,
    const int* __restrict__ ids, int sA, int nA, int sB, int nB,
    float* __restrict__ opA, float* __restrict__ opB, int lane)
{
    const int half = lane >> 5;
    const int l5 = lane & 31;
    float a0 = 0.f, a1 = 0.f, a2 = 0.f, a3 = 0.f;
    const int nmax = (nA > nB) ? nA : nB;
    int j = 0;
    while (j < nmax) {
        float r0, r1, r2, r3, r4, r5, r6, r7;
#define ISS32(k)                                                              \
        { const int jj = j + k;                                               \
          const int iA = ids[(nA > 0) ? (sA + ((jj < nA) ? jj : (nA - 1))) : 0]; \
          const int iB = ids[(nB > 0) ? (sB + ((jj < nB) ? jj : (nB - 1))) : 0]; \
          const float* pp = W + (size_t)(half ? iB : iA) * 32 + l5;           \
          asm volatile("global_load_dword %0, %1, off"                        \
                       : "=v"(r##k) : "v"(pp)); }
        ISS32(0) ISS32(1) ISS32(2) ISS32(3) ISS32(4) ISS32(5) ISS32(6) ISS32(7)
#undef ISS32
        asm volatile("s_waitcnt vmcnt(0)");
        __builtin_amdgcn_sched_barrier(0);
#define ACM32(k, d)                                                           \
        { const float mA_ = (j + k < nA) ? 1.f : 0.f;                         \
          const float mB_ = (j + k < nB) ? 1.f : 0.f;                         \
          const float m_ = half ? mB_ : mA_;                                  \
          a##d = fmaf(m_, r##k, a##d); }
        ACM32(0,0) ACM32(1,1) ACM32(2,2) ACM32(3,3)
        ACM32(4,0) ACM32(5,1) ACM32(6,2) ACM32(7,3)
#undef ACM32
        j += 8;
    }
    const float a = (a0 + a1) + (a2 + a3);
    (half ? opB : opA)[l5] = a;
}

// grid = 7 * 2048 blocks of 256 (4 waves). 7-cycle {0,1,2,3,0,1,3} gives
// T0:T1:T2:T3 = 4096:4096:2048:4096 blocks, interleaved for co-residency.
__global__ void __launch_bounds__(256) pool_fused(Ptrs p) {
    const int b = blockIdx.x;
    const int c = b / 7, r = b % 7;
    int t, within;
    switch (r) {
    case 0: t = 0; within = c * 2;     break;
    case 1: t = 1; within = c * 2;     break;
    case 2: t = 2; within = c;         break;
    case 3: t = 3; within = c * 2;     break;
    case 4: t = 0; within = c * 2 + 1; break;
    case 5: t = 1; within = c * 2 + 1; break;
    default: t = 3; within = c * 2 + 1; break;
    }
    const int wid = rfl((int)threadIdx.x >> 6);
    const int lane = threadIdx.x & 63;

    if (t == 2) {
        const int pidx = within * 4 + wid;        // 0..8191
        const int bagA = 2 * pidx, bagB = 2 * pidx + 1;
        const int sA = rfl(p.starts[2][bagA]);
        const int nA = rfl(p.lens[2][bagA]);
        const int sB = rfl(p.starts[2][bagB]);
        const int nB = rfl(p.lens[2][bagB]);
        wave_d32x2(p.W[2], p.ids[2], sA, nA, sB, nB,
                   p.out + (size_t)bagA * OUT_STRIDE + 192,
                   p.out + (size_t)bagB * OUT_STRIDE + 192, lane);
    } else if (t == 1) {
        const int bag = within * 4 + wid;
        const int s = rfl(p.starts[1][bag]);
        const int n = rfl(p.lens[1][bag]);
        wave_d128(p.W[1], p.ids[1], s, n,
                  p.out + (size_t)bag * OUT_STRIDE + 64, lane);
    } else {
        const int bag = within * 4 + wid;
        const int s = rfl(p.starts[t][bag]);
        const int n = rfl(p.lens[t][bag]);
        wave_d64(p.W[t], p.ids[t], s, n,
                 p.out + (size_t)bag * OUT_STRIDE + (t == 0 ? 0 : 224), lane);
    }
}

extern "C" void kernel_launch(void* const* d_in, const int* in_sizes, int n_in,
                              void* d_out, int out_size, void* d_ws, size_t ws_size,
                              hipStream_t stream) {
    Ptrs p;
    for (int t = 0; t < 4; ++t) {
        p.W[t]    = (const float*)d_in[3 * t + 0];
        p.ids[t]  = (const int*)d_in[3 * t + 1];
        p.lens[t] = (const int*)d_in[3 * t + 2];
        p.starts[t] = (int*)d_ws + t * NBAGS;
    }
    p.out = (float*)d_out;

    scan_kernel<<<1024, 256, 0, stream>>>(p);
    pool_fused<<<7 * 2048, 256, 0, stream>>>(p);
}

// Round 7
// 136.652 us; speedup vs baseline: 1.0915x; 1.0915x over previous
//
#include <hip/hip_runtime.h>
#include <hip/hip_bf16.h>

#define NBAGS 16384
#define OUT_STRIDE 288

struct Ptrs {
    const float* W[4];
    const int* ids[4];
    const int* lens[4];
    int* starts[4];
    float* out;
};

// Brute-force chunked exclusive scan: grid = 4 tables x 256 chunks.
__global__ void __launch_bounds__(256) scan_kernel(Ptrs p) {
    const int t = blockIdx.x >> 8;
    const int c = blockIdx.x & 255;
    const int* __restrict__ lens = p.lens[t];
    int* __restrict__ starts = p.starts[t];
    const int tid = threadIdx.x;
    const int P = c * 64;

    __shared__ int red[256];
    int s = 0;
    for (int k = tid; k < P; k += 256) s += lens[k];
    red[tid] = s;
    __syncthreads();
    for (int off = 128; off > 0; off >>= 1) {
        if (tid < off) red[tid] += red[tid + off];
        __syncthreads();
    }
    const int prefix = red[0];

    if (tid < 64) {
        const int v = lens[P + tid];
        int inc = v;
#pragma unroll
        for (int off = 1; off < 64; off <<= 1) {
            int u = __shfl_up(inc, off, 64);
            if (tid >= off) inc += u;
        }
        starts[P + tid] = prefix + inc - v;
    }
}

// One unit = 8 bags, 256 threads; G groups of TPB=D/4 lanes per bag.
// Double-buffered id batches, masked tails; uniform work per block with all
// four tables interleaved across the grid. This structure measured best
// (136.4 us) and sits at the random-gather HBM service roofline:
// FETCH_SIZE == compulsory unique-row footprint (~397 MB) at ~3.0 TB/s.
template <int D, int G, int U>
__device__ __forceinline__ void pool_unit(
    const float* __restrict__ W, const int* __restrict__ ids,
    const int* __restrict__ starts, const int* __restrict__ lens,
    float* __restrict__ out, int col_off, int chunk, float4* sm)
{
    constexpr int TPB = D / 4;             // lanes per group
    constexpr int SLOTS = 256 / (TPB * G); // bags per block (8 everywhere)
    constexpr unsigned RB = (unsigned)(D * 4);  // row bytes
    const int tid = threadIdx.x;
    const int slot = tid / (TPB * G);
    const int g = (tid / TPB) % G;
    const int lane = tid % TPB;
    const int bag = chunk * SLOTS + slot;
    const int s = starts[bag];
    const int n = lens[bag];
    const char* __restrict__ Wb = reinterpret_cast<const char*>(W);
    const unsigned lane16 = (unsigned)(lane * 16);

    float4 acc[U];
#pragma unroll
    for (int u = 0; u < U; ++u) acc[u] = make_float4(0.f, 0.f, 0.f, 0.f);

    // batch b covers rows j = g + (b*U + u)*G for u in [0,U)
    int j0 = g;
    int idxA[U];
#pragma unroll
    for (int u = 0; u < U; ++u) {
        const int jj = j0 + u * G;
        idxA[u] = (jj < n) ? ids[s + jj] : -1;
    }

    while (true) {
        float4 r[U];
#pragma unroll
        for (int u = 0; u < U; ++u) {
            const int id = idxA[u];
            const unsigned off = (unsigned)(id < 0 ? 0 : id) * RB + lane16;
            r[u] = *reinterpret_cast<const float4*>(Wb + off);
        }
        const int j1 = j0 + U * G;
        int idxB[U];
#pragma unroll
        for (int u = 0; u < U; ++u) {
            const int jj = j1 + u * G;
            idxB[u] = (jj < n) ? ids[s + jj] : -1;
        }
#pragma unroll
        for (int u = 0; u < U; ++u) {
            const float m = (idxA[u] >= 0) ? 1.f : 0.f;
            acc[u].x = fmaf(m, r[u].x, acc[u].x);
            acc[u].y = fmaf(m, r[u].y, acc[u].y);
            acc[u].z = fmaf(m, r[u].z, acc[u].z);
            acc[u].w = fmaf(m, r[u].w, acc[u].w);
        }
        j0 = j1;
        if (j0 >= n) break;
#pragma unroll
        for (int u = 0; u < U; ++u) idxA[u] = idxB[u];
    }

#pragma unroll
    for (int u = 1; u < U; ++u) {
        acc[0].x += acc[u].x; acc[0].y += acc[u].y;
        acc[0].z += acc[u].z; acc[0].w += acc[u].w;
    }

    if constexpr (G == 1) {
        float4* o = reinterpret_cast<float4*>(out + (size_t)bag * OUT_STRIDE + col_off) + lane;
        *o = acc[0];
    } else {
        sm[tid] = acc[0];
        __syncthreads();
        if (g == 0) {
#pragma unroll
            for (int h = 1; h < G; ++h) {
                const float4 v = sm[tid + h * TPB];
                acc[0].x += v.x; acc[0].y += v.y; acc[0].z += v.z; acc[0].w += v.w;
            }
            float4* o = reinterpret_cast<float4*>(out + (size_t)bag * OUT_STRIDE + col_off) + lane;
            *o = acc[0];
        }
    }
}

// grid = 8192: unit u -> table u&3, chunk u>>2; uniform work per block.
__global__ void __launch_bounds__(256) pool_fused(Ptrs p) {
    __shared__ float4 sm[256];
    const int u = blockIdx.x;
    const int chunk = u >> 2;
    switch (u & 3) {
    case 0: pool_unit<64, 2, 8>(p.W[0], p.ids[0], p.starts[0], p.lens[0], p.out, 0,   chunk, sm); break;
    case 1: pool_unit<128, 1, 8>(p.W[1], p.ids[1], p.starts[1], p.lens[1], p.out, 64,  chunk, sm); break;
    case 2: pool_unit<32, 4, 8>(p.W[2], p.ids[2], p.starts[2], p.lens[2], p.out, 192, chunk, sm); break;
    default: pool_unit<64, 2, 8>(p.W[3], p.ids[3], p.starts[3], p.lens[3], p.out, 224, chunk, sm); break;
    }
}

extern "C" void kernel_launch(void* const* d_in, const int* in_sizes, int n_in,
                              void* d_out, int out_size, void* d_ws, size_t ws_size,
                              hipStream_t stream) {
    Ptrs p;
    for (int t = 0; t < 4; ++t) {
        p.W[t]    = (const float*)d_in[3 * t + 0];
        p.ids[t]  = (const int*)d_in[3 * t + 1];
        p.lens[t] = (const int*)d_in[3 * t + 2];
        p.starts[t] = (int*)d_ws + t * NBAGS;
    }
    p.out = (float*)d_out;

    scan_kernel<<<1024, 256, 0, stream>>>(p);
    pool_fused<<<NBAGS / 8 * 4, 256, 0, stream>>>(p);
}